// Round 4
// baseline (7545.203 us; speedup 1.0000x reference)
//
#include <hip/hip_runtime.h>
#include <math.h>

#define DD 64

// ============================ CSR build kernels ============================

__global__ void hist_kernel(int* __restrict__ cnt, const int* __restrict__ tgt, int E) {
    int g = blockIdx.x * blockDim.x + threadIdx.x;
    int stride = gridDim.x * blockDim.x;
    for (int e = g; e < E; e += stride) atomicAdd(&cnt[tgt[e]], 1);
}

// exclusive scan of cnt[0..n) -> ptr[0..n] AND cursor[0..n) (cursor may alias cnt)
__global__ void scan_kernel(int* __restrict__ ptr, int* __restrict__ cursor,
                            const int* __restrict__ cnt, int n) {
    __shared__ int part[1024];
    int t = threadIdx.x;
    int per = (n + 1023) / 1024;
    int lo = t * per;
    int hi = lo + per; if (hi > n) hi = n; if (lo > n) lo = n;
    int s = 0;
    for (int i = lo; i < hi; ++i) s += cnt[i];
    part[t] = s;
    __syncthreads();
    for (int off = 1; off < 1024; off <<= 1) {
        int v = (t >= off) ? part[t - off] : 0;
        __syncthreads();
        part[t] += v;
        __syncthreads();
    }
    int run = (t == 0) ? 0 : part[t - 1];
    for (int i = lo; i < hi; ++i) {
        int c = cnt[i];           // read before cursor write (cursor may alias cnt)
        ptr[i] = run;
        cursor[i] = run;
        run += c;
    }
    if (t == 1023) ptr[n] = part[1023];
}

// perm[pos] = edge-id grouped by tgt[e]; cursor pre-loaded with ptr
__global__ void scatter_perm_kernel(int* __restrict__ perm, int* __restrict__ cursor,
                                    const int* __restrict__ tgt, int E) {
    int g = blockIdx.x * blockDim.x + threadIdx.x;
    int stride = gridDim.x * blockDim.x;
    for (int e = g; e < E; e += stride) {
        int p = atomicAdd(&cursor[tgt[e]], 1);
        perm[p] = e;
    }
}

// ======================= gather-based segmented SpMM =======================
// one wave per output row; lane = dim.
// out[r] = (sum_e val_e*in[src_e] + add1[r] + add2[r]) * scale
// optional dual: out2[r] = (sum_e val_e*in2[src_e]) * scale
__global__ void spmm_csr_kernel(float* __restrict__ out, const float* __restrict__ in,
                                const int* __restrict__ perm, const int* __restrict__ ptr,
                                const int* __restrict__ srcarr, const float* __restrict__ valarr,
                                int nrows,
                                const float* __restrict__ add1, const float* __restrict__ add2,
                                float scale,
                                const float* __restrict__ in2, float* __restrict__ out2) {
    int w = (int)(((unsigned)blockIdx.x * blockDim.x + threadIdx.x) >> 6);
    int lane = threadIdx.x & 63;
    if (w >= nrows) return;
    int p = ptr[w];
    int end = ptr[w + 1];
    size_t rowoff = (size_t)w * DD + lane;
    float acc = 0.f, acc2 = 0.f;
    const bool dual = (in2 != nullptr);
    for (; p + 8 <= end; p += 8) {
        int ee[8], ss[8];
        float vv[8];
#pragma unroll
        for (int k = 0; k < 8; ++k) ee[k] = __builtin_amdgcn_readfirstlane(perm[p + k]);
#pragma unroll
        for (int k = 0; k < 8; ++k) ss[k] = __builtin_amdgcn_readfirstlane(srcarr[ee[k]]);
#pragma unroll
        for (int k = 0; k < 8; ++k)
            vv[k] = __int_as_float(__builtin_amdgcn_readfirstlane(__float_as_int(valarr[ee[k]])));
#pragma unroll
        for (int k = 0; k < 8; ++k) acc += vv[k] * in[(size_t)ss[k] * DD + lane];
        if (dual) {
#pragma unroll
            for (int k = 0; k < 8; ++k) acc2 += vv[k] * in2[(size_t)ss[k] * DD + lane];
        }
    }
    for (; p < end; ++p) {
        int e = __builtin_amdgcn_readfirstlane(perm[p]);
        int s = __builtin_amdgcn_readfirstlane(srcarr[e]);
        float v = __int_as_float(__builtin_amdgcn_readfirstlane(__float_as_int(valarr[e])));
        acc += v * in[(size_t)s * DD + lane];
        if (dual) acc2 += v * in2[(size_t)s * DD + lane];
    }
    if (add1) acc += add1[rowoff];
    if (add2) acc += add2[rowoff];
    out[rowoff] = acc * scale;
    if (dual) out2[rowoff] = acc2 * scale;
}

// ===================== fallback atomic SpMM (safety net) =====================
__global__ void spmm_atomic_kernel(float* __restrict__ out, const float* __restrict__ in,
                                   const int* __restrict__ tgt, const int* __restrict__ src,
                                   const float* __restrict__ val, long long nwork) {
    long long g = (long long)blockIdx.x * blockDim.x + threadIdx.x;
    long long stride = (long long)gridDim.x * blockDim.x;
    for (long long t = g; t < nwork; t += stride) {
        int e = (int)(t >> 4);
        int c = (int)(t & 15);
        int s = src[e];
        int dt = tgt[e];
        float v = val[e];
        float4 x = ((const float4*)(in + (size_t)s * DD))[c];
        float* o = out + (size_t)dt * DD + (size_t)c * 4;
        unsafeAtomicAdd(o + 0, v * x.x);
        unsafeAtomicAdd(o + 1, v * x.y);
        unsafeAtomicAdd(o + 2, v * x.z);
        unsafeAtomicAdd(o + 3, v * x.w);
    }
}

// ============================= dense helpers ==============================

__global__ void avg3_kernel(float4* __restrict__ io, const float4* __restrict__ a,
                            const float4* __restrict__ b, long long n4) {
    long long g = (long long)blockIdx.x * blockDim.x + threadIdx.x;
    long long stride = (long long)gridDim.x * blockDim.x;
    const float k = 1.0f / 3.0f;
    for (long long i = g; i < n4; i += stride) {
        float4 x = io[i], y = a[i], z = b[i];
        x.x = (x.x + y.x + z.x) * k;
        x.y = (x.y + y.y + z.y) * k;
        x.z = (x.z + y.z + z.z) * k;
        x.w = (x.w + y.w + z.w) * k;
        io[i] = x;
    }
}

__global__ void gather_kernel(float* __restrict__ out, const float* __restrict__ src,
                              const int* __restrict__ idx, int nrows) {
    int g = blockIdx.x * blockDim.x + threadIdx.x;
    if (g >= nrows * DD) return;
    int r = g >> 6;
    out[g] = src[(size_t)idx[r] * DD + (g & 63)];
}

__global__ void gather_norm_kernel(float* __restrict__ out, const float* __restrict__ src,
                                   const int* __restrict__ idx, int nrows, int istride) {
    int r = blockIdx.x;
    if (r >= nrows) return;
    int d = threadIdx.x;
    float v = src[(size_t)idx[(size_t)r * istride] * DD + d];
    float ss = v * v;
#pragma unroll
    for (int o = 32; o >= 1; o >>= 1) ss += __shfl_xor(ss, o);
    out[(size_t)r * DD + d] = v * rsqrtf(ss + 1e-8f);
}

// out[64][n] = in[n][64]^T  (LDS tile transpose, grid = n/64, block = 256)
__global__ void transpose64_kernel(float* __restrict__ out, const float* __restrict__ in,
                                   int n) {
    __shared__ float T[64][65];
    int b0 = blockIdx.x * 64;
    int t = threadIdx.x;
#pragma unroll
    for (int k = 0; k < 4; ++k) {
        int f = k * 1024 + t * 4;
        int r = f >> 6, c = f & 63;
        float4 v = *(const float4*)(in + (size_t)(b0 + r) * 64 + c);
        T[r][c] = v.x; T[r][c + 1] = v.y; T[r][c + 2] = v.z; T[r][c + 3] = v.w;
    }
    __syncthreads();
#pragma unroll
    for (int k = 0; k < 4; ++k) {
        int f = k * 1024 + t * 4;
        int d = f >> 6, c = f & 63;
        float4 v;
        v.x = T[c][d]; v.y = T[c + 1][d]; v.z = T[c + 2][d]; v.w = T[c + 3][d];
        *(float4*)(out + (size_t)d * n + b0 + c) = v;
    }
}

__global__ void batch_pred_kernel(const float* __restrict__ u1, const float* __restrict__ u2,
                                  const float* __restrict__ u3b,
                                  const float* __restrict__ b1, const float* __restrict__ b2,
                                  const float* __restrict__ b3,
                                  const int* __restrict__ uidx, const int* __restrict__ bidx,
                                  const float* __restrict__ W1, const float* __restrict__ c1,
                                  const float* __restrict__ W2, const float* __restrict__ c2,
                                  const float* __restrict__ W3, const float* __restrict__ c3,
                                  float* __restrict__ acc, int nb) {
    int b = blockIdx.x;
    if (b >= nb) return;
    int d = threadIdx.x;
    int u = uidx[b];
    float ud1 = u1[(size_t)u * DD + d];
    float ud2 = u2[(size_t)u * DD + d];
    float ud3 = u3b[(size_t)b * DD + d];
    float pred[2];
#pragma unroll
    for (int p = 0; p < 2; ++p) {
        int bi = bidx[b * 2 + p];
        float s0 = ud1 * b1[(size_t)bi * DD + d];
        float s1 = ud2 * b2[(size_t)bi * DD + d];
        float s2 = ud3 * b3[(size_t)bi * DD + d];
#pragma unroll
        for (int o = 32; o >= 1; o >>= 1) {
            s0 += __shfl_xor(s0, o);
            s1 += __shfl_xor(s1, o);
            s2 += __shfl_xor(s2, o);
        }
        float t0 = tanhf(s0 * W1[0] + s1 * W1[1] + s2 * W1[2] + c1[0]);
        float t1 = tanhf(s0 * W1[3] + s1 * W1[4] + s2 * W1[5] + c1[1]);
        float t2 = tanhf(s0 * W1[6] + s1 * W1[7] + s2 * W1[8] + c1[2]);
        float g0 = tanhf(t0 * W2[0] + t1 * W2[1] + t2 * W2[2] + c2[0]);
        float g1 = tanhf(t0 * W2[3] + t1 * W2[4] + t2 * W2[5] + c2[1]);
        float g2 = tanhf(t0 * W2[6] + t1 * W2[7] + t2 * W2[8] + c2[2]);
        pred[p] = g0 * W3[0] + g1 * W3[1] + g2 * W3[2] + c3[0];
    }
    if (d == 0) {
        float x = pred[1] - pred[0];
        float sp = (x > 20.0f) ? x : log1pf(expf(x));
        unsafeAtomicAdd(acc, sp);
    }
}

// per row i (1 wave): logsumexp_j(A_i . Bt_j / temp) - diag.
// A row-major [n][64] (row cached in regs), Bt d-major [64][n] (coalesced).
__global__ void nce_kernel(const float* __restrict__ A, const float* __restrict__ Bt,
                           float* __restrict__ acc, int n, float invtemp) {
    int wv = threadIdx.x >> 6;
    int lane = threadIdx.x & 63;
    int row = blockIdx.x * 4 + wv;
    float4 a4[16];
    const float4* Ap = (const float4*)(A + (size_t)row * DD);
#pragma unroll
    for (int q = 0; q < 16; ++q) a4[q] = Ap[q];
    float m = -1e30f, ssum = 0.0f, diag = 0.0f;
    int ntile = n >> 6;
    for (int t = 0; t < ntile; ++t) {
        int j = (t << 6) + lane;
        const float* c = Bt + j;
        float dot = 0.0f;
#pragma unroll
        for (int q = 0; q < 16; ++q) {
            float4 a = a4[q];
            dot += a.x * c[(size_t)(4 * q + 0) * n]
                 + a.y * c[(size_t)(4 * q + 1) * n]
                 + a.z * c[(size_t)(4 * q + 2) * n]
                 + a.w * c[(size_t)(4 * q + 3) * n];
        }
        float lg = dot * invtemp;
        if (j == row) diag = lg;
        float mn = fmaxf(m, lg);
        ssum = ssum * __expf(m - mn) + __expf(lg - mn);
        m = mn;
    }
#pragma unroll
    for (int o = 32; o >= 1; o >>= 1) {
        float m2 = __shfl_xor(m, o);
        float s2 = __shfl_xor(ssum, o);
        float d2 = __shfl_xor(diag, o);
        float mn = fmaxf(m, m2);
        ssum = ssum * __expf(m - mn) + s2 * __expf(m2 - mn);
        m = mn;
        diag += d2;
    }
    if (lane == 0) unsafeAtomicAdd(acc, m + logf(ssum) - diag);
}

__global__ void final_kernel(const float* __restrict__ acc, float* __restrict__ out,
                             float invn, float alpha) {
    out[0] = acc[0] * invn + alpha * invn * (acc[1] + acc[2]);
}

// ================================ driver ==================================

extern "C" void kernel_launch(void* const* d_in, const int* in_sizes, int n_in,
                              void* d_out, int out_size, void* d_ws, size_t ws_size,
                              hipStream_t stream) {
    const float* users_feat   = (const float*)d_in[0];
    const float* bundles_feat = (const float*)d_in[1];
    const float* items_feat   = (const float*)d_in[2];
    const float* W1 = (const float*)d_in[3];
    const float* c1 = (const float*)d_in[4];
    const float* W2 = (const float*)d_in[5];
    const float* c2 = (const float*)d_in[6];
    const float* W3 = (const float*)d_in[7];
    const float* c3 = (const float*)d_in[8];
    const float* ui_val = (const float*)d_in[9];
    const float* ub_val = (const float*)d_in[10];
    const float* bi_val = (const float*)d_in[11];
    const int* ui_row = (const int*)d_in[12];
    const int* ui_col = (const int*)d_in[13];
    const int* ub_row = (const int*)d_in[14];
    const int* ub_col = (const int*)d_in[15];
    const int* bi_row = (const int*)d_in[16];
    const int* bi_col = (const int*)d_in[17];
    const int* uidx = (const int*)d_in[18];
    const int* bidx = (const int*)d_in[19];

    const int U  = in_sizes[0] / DD;
    const int NB = in_sizes[1] / DD;
    const int I  = in_sizes[2] / DD;
    const int Eui = in_sizes[9];
    const int Eub = in_sizes[10];
    const int Ebi = in_sizes[11];
    const int BT = in_sizes[18];

    const size_t U64  = (size_t)U * DD;
    const size_t I64  = (size_t)I * DD;
    const size_t NB64 = (size_t)NB * DD;
    size_t R2sz = 2 * I64; if (R2sz < U64) R2sz = U64;

    // ---------------- float buffer layout (overlaid) ----------------
    float* w = (float*)d_ws;
    size_t o = 0;
    float* T_U1 = w + o; o += U64;    // x1a, then y1a
    float* R2   = w + o; o += R2sz;   // [x1b | i1] then u2
    float* T_I1 = R2;                 // x1b
    float* T_I2 = R2 + I64;           // i1
    float* u2   = R2;
    float* u1   = w + o; o += U64;
    float* b1   = w + o; o += NB64;
    float* b3   = w + o; o += NB64;
    float* y1b  = w + o; o += NB64;
    float* b2   = w + o; o += NB64;
    float* u3b  = w + o; o += (size_t)BT * DD;
    float* A1   = w + o; o += (size_t)BT * DD;
    float* A2   = w + o; o += (size_t)BT * DD;
    float* B1n  = w + o; o += (size_t)BT * DD;
    float* B2n  = w + o; o += (size_t)BT * DD;
    float* acc  = w + o; o += 16;

    // ---------------- int area: one shared perm/ptr/cnt ----------------
    int nmax = U; if (I > nmax) nmax = I; if (NB > nmax) nmax = NB;
    int emax = Eui; if (Eub > emax) emax = Eub; if (Ebi > emax) emax = Ebi;
    int* ib = (int*)(w + o);
    size_t io_ = 0;
    int* cnt  = ib + io_; io_ += (size_t)nmax + 1;
    int* ptr_ = ib + io_; io_ += (size_t)nmax + 1;
    int* perm = ib + io_; io_ += (size_t)emax;
    size_t needed = o * sizeof(float) + io_ * sizeof(int);

    // transposed NCE operands overlay the (dead-by-then) int area
    float* A2t = (float*)ib;                       // [64][BT]
    float* B2t = A2t + (size_t)BT * DD;            // [64][BT]

    auto avg3 = [&](float* io2, const float* a, const float* b, long long n) {
        long long n4 = n / 4;
        long long nb_ = (n4 + 255) / 256;
        int blocks = (int)(nb_ > 4096 ? 4096 : nb_);
        avg3_kernel<<<blocks, 256, 0, stream>>>((float4*)io2, (const float4*)a,
                                                (const float4*)b, n4);
    };

    if (ws_size >= needed) {
        // ---------------- CSR gather path (no float atomics) ----------------
        auto build = [&](const int* tgt, int n, int E) {
            hipMemsetAsync(cnt, 0, ((size_t)n + 1) * sizeof(int), stream);
            int gb = (E + 255) / 256; if (gb > 4096) gb = 4096;
            hist_kernel<<<gb, 256, 0, stream>>>(cnt, tgt, E);
            scan_kernel<<<1, 1024, 0, stream>>>(ptr_, cnt, cnt, n);  // cursor aliases cnt
            scatter_perm_kernel<<<gb, 256, 0, stream>>>(perm, cnt, tgt, E);
        };
        auto spmm = [&](float* out_, const float* in_, const int* srcarr,
                        const float* valarr, int nrows,
                        const float* add1, const float* add2, float scale,
                        const float* in2, float* out2) {
            int blocks = (nrows + 3) / 4;
            spmm_csr_kernel<<<blocks, 256, 0, stream>>>(out_, in_, perm, ptr_,
                                                        srcarr, valarr, nrows,
                                                        add1, add2, scale, in2, out2);
        };
        const float k3 = 1.0f / 3.0f;

        // ---- View 1 (u-i); u3 == x1a ----
        build(ui_row, U, Eui);
        spmm(T_U1, items_feat, ui_col, ui_val, U, nullptr, nullptr, 1.f, nullptr, nullptr); // x1a
        build(ui_col, I, Eui);
        spmm(T_I1, users_feat, ui_row, ui_val, I, nullptr, nullptr, 1.f, nullptr, nullptr); // x1b
        spmm(T_I2, T_U1, ui_row, ui_val, I, items_feat, T_I1, k3, nullptr, nullptr);        // i1
        build(ui_row, U, Eui);
        spmm(u1, T_I1, ui_col, ui_val, U, users_feat, T_U1, k3, nullptr, nullptr);          // u1
        gather_kernel<<<(BT * DD + 255) / 256, 256, 0, stream>>>(u3b, T_U1, uidx, BT);
        build(bi_row, NB, Ebi);
        spmm(b1, T_I2, bi_col, bi_val, NB, nullptr, nullptr, 1.f, items_feat, b3);          // b1 + b3

        // ---- View 2 (u-b) ----
        build(ub_row, U, Eub);
        spmm(T_U1, bundles_feat, ub_col, ub_val, U, nullptr, nullptr, 1.f, nullptr, nullptr); // y1a
        build(ub_col, NB, Eub);
        spmm(y1b, users_feat, ub_row, ub_val, NB, nullptr, nullptr, 1.f, nullptr, nullptr);   // y1b
        spmm(b2, T_U1, ub_row, ub_val, NB, bundles_feat, y1b, k3, nullptr, nullptr);          // b2
        build(ub_row, U, Eub);
        spmm(u2, y1b, ub_col, ub_val, U, users_feat, T_U1, k3, nullptr, nullptr);             // u2
    } else {
        // ---------------- atomic fallback ----------------
        auto spmm_at = [&](float* out_, const float* in_, const int* tgt, const int* src,
                           const float* val, int E, size_t outfloats) {
            hipMemsetAsync(out_, 0, outfloats * sizeof(float), stream);
            long long nwork = (long long)E * 16;
            long long nb_ = (nwork + 255) / 256;
            int blocks = (int)(nb_ > 16384 ? 16384 : nb_);
            spmm_atomic_kernel<<<blocks, 256, 0, stream>>>(out_, in_, tgt, src, val, nwork);
        };
        spmm_at(T_U1, items_feat, ui_row, ui_col, ui_val, Eui, U64);
        spmm_at(T_I1, users_feat, ui_col, ui_row, ui_val, Eui, I64);
        spmm_at(T_I2, T_U1, ui_col, ui_row, ui_val, Eui, I64);
        spmm_at(u1, T_I1, ui_row, ui_col, ui_val, Eui, U64);
        gather_kernel<<<(BT * DD + 255) / 256, 256, 0, stream>>>(u3b, T_U1, uidx, BT);
        avg3(u1, users_feat, T_U1, (long long)U64);
        avg3(T_I2, items_feat, T_I1, (long long)I64);
        spmm_at(b1, T_I2, bi_row, bi_col, bi_val, Ebi, NB64);
        spmm_at(b3, items_feat, bi_row, bi_col, bi_val, Ebi, NB64);
        spmm_at(T_U1, bundles_feat, ub_row, ub_col, ub_val, Eub, U64);
        spmm_at(y1b, users_feat, ub_col, ub_row, ub_val, Eub, NB64);
        spmm_at(b2, T_U1, ub_col, ub_row, ub_val, Eub, NB64);
        spmm_at(u2, y1b, ub_row, ub_col, ub_val, Eub, U64);
        avg3(u2, users_feat, T_U1, (long long)U64);
        avg3(b2, bundles_feat, y1b, (long long)NB64);
    }

    // ---- batch gathers + normalized views for InfoNCE ----
    gather_norm_kernel<<<BT, 64, 0, stream>>>(A1, u1, uidx, BT, 1);
    gather_norm_kernel<<<BT, 64, 0, stream>>>(A2, u2, uidx, BT, 1);
    gather_norm_kernel<<<BT, 64, 0, stream>>>(B1n, b1, bidx, BT, 2);
    gather_norm_kernel<<<BT, 64, 0, stream>>>(B2n, b2, bidx, BT, 2);
    // transpose the B-side operands (into dead CSR area)
    transpose64_kernel<<<BT / 64, 256, 0, stream>>>(A2t, A2, BT);
    transpose64_kernel<<<BT / 64, 256, 0, stream>>>(B2t, B2n, BT);

    hipMemsetAsync(acc, 0, 4 * sizeof(float), stream);

    batch_pred_kernel<<<BT, 64, 0, stream>>>(u1, u2, u3b, b1, b2, b3, uidx, bidx,
                                             W1, c1, W2, c2, W3, c3, acc, BT);

    nce_kernel<<<BT / 4, 256, 0, stream>>>(A1, A2t, acc + 1, BT, 4.0f);
    nce_kernel<<<BT / 4, 256, 0, stream>>>(B1n, B2t, acc + 2, BT, 4.0f);

    final_kernel<<<1, 1, 0, stream>>>(acc, (float*)d_out, 1.0f / (float)BT, 0.5f);
}

// Round 5
// 5211.067 us; speedup vs baseline: 1.4479x; 1.4479x over previous
//
#include <hip/hip_runtime.h>
#include <math.h>

#define DD 64
#define SCAN_TPB 256
#define SCAN_EPT 8
#define SCAN_EPB (SCAN_TPB * SCAN_EPT)  // 2048 elements per block

// ============================ CSR build kernels ============================

__global__ void hist_kernel(int* __restrict__ cnt, const int* __restrict__ tgt, int E) {
    int g = blockIdx.x * blockDim.x + threadIdx.x;
    int stride = gridDim.x * blockDim.x;
    for (int e = g; e < E; e += stride) atomicAdd(&cnt[tgt[e]], 1);
}

// pass1: blocksum[b] = sum cnt[b*2048 .. b*2048+2047]
__global__ void scan_pass1(int* __restrict__ blocksum, const int* __restrict__ cnt, int n) {
    int base = blockIdx.x * SCAN_EPB + threadIdx.x * SCAN_EPT;
    int s = 0;
#pragma unroll
    for (int k = 0; k < SCAN_EPT; ++k) {
        int i = base + k;
        if (i < n) s += cnt[i];
    }
#pragma unroll
    for (int o = 32; o >= 1; o >>= 1) s += __shfl_xor(s, o);
    __shared__ int ws_[4];
    if ((threadIdx.x & 63) == 0) ws_[threadIdx.x >> 6] = s;
    __syncthreads();
    if (threadIdx.x == 0) blocksum[blockIdx.x] = ws_[0] + ws_[1] + ws_[2] + ws_[3];
}

// pass2: in-place exclusive scan of blocksum[0..nb) (nb <= 1024); ptr_n[0] = total
__global__ void scan_pass2(int* __restrict__ blocksum, int nb, int* __restrict__ ptr_n) {
    __shared__ int sh[1024];
    int t = threadIdx.x;
    int v = (t < nb) ? blocksum[t] : 0;
    sh[t] = v;
    __syncthreads();
    for (int o = 1; o < 1024; o <<= 1) {
        int x = (t >= o) ? sh[t - o] : 0;
        __syncthreads();
        sh[t] += x;
        __syncthreads();
    }
    if (t < nb) blocksum[t] = sh[t] - v;  // exclusive
    if (t == nb - 1) ptr_n[0] = sh[t];    // total edge count
}

// pass3: ptr[i] = cursor[i] = blockoff[b] + intra-block exclusive scan (cursor may alias cnt)
__global__ void scan_pass3(int* __restrict__ ptr, int* __restrict__ cursor,
                           const int* __restrict__ cnt, const int* __restrict__ blockoff,
                           int n) {
    int base = blockIdx.x * SCAN_EPB + threadIdx.x * SCAN_EPT;
    int vals[SCAN_EPT];
    int s = 0;
#pragma unroll
    for (int k = 0; k < SCAN_EPT; ++k) {
        int i = base + k;
        int c = (i < n) ? cnt[i] : 0;
        vals[k] = s;   // exclusive within thread
        s += c;
    }
    int incl = s;
#pragma unroll
    for (int o = 1; o < 64; o <<= 1) {
        int x = __shfl_up(incl, o);
        if ((threadIdx.x & 63) >= o) incl += x;
    }
    __shared__ int wtot[4];
    if ((threadIdx.x & 63) == 63) wtot[threadIdx.x >> 6] = incl;
    __syncthreads();
    int woff = 0;
    int wv = threadIdx.x >> 6;
    for (int k = 0; k < 4; ++k)
        if (k < wv) woff += wtot[k];
    int texcl = incl - s + woff + blockoff[blockIdx.x];
#pragma unroll
    for (int k = 0; k < SCAN_EPT; ++k) {
        int i = base + k;
        if (i < n) {
            int p = texcl + vals[k];
            ptr[i] = p;
            cursor[i] = p;
        }
    }
}

// perm[pos] = edge-id grouped by tgt[e]; cursor pre-loaded with ptr
__global__ void scatter_perm_kernel(int* __restrict__ perm, int* __restrict__ cursor,
                                    const int* __restrict__ tgt, int E) {
    int g = blockIdx.x * blockDim.x + threadIdx.x;
    int stride = gridDim.x * blockDim.x;
    for (int e = g; e < E; e += stride) {
        int p = atomicAdd(&cursor[tgt[e]], 1);
        perm[p] = e;
    }
}

// ======================= gather-based segmented SpMM =======================
// one wave per output row; lane = dim.
//   acc  = sum_e val_e * in [src_e];   acc2 = sum_e val_e * in2[src_e]
//   out [r] = (acc  + add1[r] + add2[r]) * scale1
//   out2[r] = (acc2 + f*acc  + addB[r]) * scale2     (dual only, f in {0,1})
__global__ void spmm_csr_kernel(float* __restrict__ out, const float* __restrict__ in,
                                const int* __restrict__ perm, const int* __restrict__ ptr,
                                const int* __restrict__ srcarr, const float* __restrict__ valarr,
                                int nrows,
                                const float* __restrict__ add1, const float* __restrict__ add2,
                                float scale1,
                                const float* __restrict__ in2, float* __restrict__ out2,
                                const float* __restrict__ addB, float f, float scale2) {
    int w = (int)(((unsigned)blockIdx.x * blockDim.x + threadIdx.x) >> 6);
    int lane = threadIdx.x & 63;
    if (w >= nrows) return;
    int p = ptr[w];
    int end = ptr[w + 1];
    size_t rowoff = (size_t)w * DD + lane;
    float acc = 0.f, acc2 = 0.f;
    const bool dual = (in2 != nullptr);
    for (; p + 8 <= end; p += 8) {
        int ee[8], ss[8];
        float vv[8];
#pragma unroll
        for (int k = 0; k < 8; ++k) ee[k] = __builtin_amdgcn_readfirstlane(perm[p + k]);
#pragma unroll
        for (int k = 0; k < 8; ++k) ss[k] = __builtin_amdgcn_readfirstlane(srcarr[ee[k]]);
#pragma unroll
        for (int k = 0; k < 8; ++k)
            vv[k] = __int_as_float(__builtin_amdgcn_readfirstlane(__float_as_int(valarr[ee[k]])));
#pragma unroll
        for (int k = 0; k < 8; ++k) acc += vv[k] * in[(size_t)ss[k] * DD + lane];
        if (dual) {
#pragma unroll
            for (int k = 0; k < 8; ++k) acc2 += vv[k] * in2[(size_t)ss[k] * DD + lane];
        }
    }
    for (; p < end; ++p) {
        int e = __builtin_amdgcn_readfirstlane(perm[p]);
        int s = __builtin_amdgcn_readfirstlane(srcarr[e]);
        float v = __int_as_float(__builtin_amdgcn_readfirstlane(__float_as_int(valarr[e])));
        acc += v * in[(size_t)s * DD + lane];
        if (dual) acc2 += v * in2[(size_t)s * DD + lane];
    }
    float r = acc;
    if (add1) r += add1[rowoff];
    if (add2) r += add2[rowoff];
    out[rowoff] = r * scale1;
    if (dual) {
        float r2 = acc2 + f * acc;
        if (addB) r2 += addB[rowoff];
        out2[rowoff] = r2 * scale2;
    }
}

// ===================== fallback atomic SpMM (safety net) =====================
__global__ void spmm_atomic_kernel(float* __restrict__ out, const float* __restrict__ in,
                                   const int* __restrict__ tgt, const int* __restrict__ src,
                                   const float* __restrict__ val, long long nwork) {
    long long g = (long long)blockIdx.x * blockDim.x + threadIdx.x;
    long long stride = (long long)gridDim.x * blockDim.x;
    for (long long t = g; t < nwork; t += stride) {
        int e = (int)(t >> 4);
        int c = (int)(t & 15);
        int s = src[e];
        int dt = tgt[e];
        float v = val[e];
        float4 x = ((const float4*)(in + (size_t)s * DD))[c];
        float* o = out + (size_t)dt * DD + (size_t)c * 4;
        unsafeAtomicAdd(o + 0, v * x.x);
        unsafeAtomicAdd(o + 1, v * x.y);
        unsafeAtomicAdd(o + 2, v * x.z);
        unsafeAtomicAdd(o + 3, v * x.w);
    }
}

// ============================= dense helpers ==============================

__global__ void avg3_kernel(float4* __restrict__ io, const float4* __restrict__ a,
                            const float4* __restrict__ b, long long n4) {
    long long g = (long long)blockIdx.x * blockDim.x + threadIdx.x;
    long long stride = (long long)gridDim.x * blockDim.x;
    const float k = 1.0f / 3.0f;
    for (long long i = g; i < n4; i += stride) {
        float4 x = io[i], y = a[i], z = b[i];
        x.x = (x.x + y.x + z.x) * k;
        x.y = (x.y + y.y + z.y) * k;
        x.z = (x.z + y.z + z.z) * k;
        x.w = (x.w + y.w + z.w) * k;
        io[i] = x;
    }
}

__global__ void gather_kernel(float* __restrict__ out, const float* __restrict__ src,
                              const int* __restrict__ idx, int nrows) {
    int g = blockIdx.x * blockDim.x + threadIdx.x;
    if (g >= nrows * DD) return;
    int r = g >> 6;
    out[g] = src[(size_t)idx[r] * DD + (g & 63)];
}

__global__ void gather_norm_kernel(float* __restrict__ out, const float* __restrict__ src,
                                   const int* __restrict__ idx, int nrows, int istride) {
    int r = blockIdx.x;
    if (r >= nrows) return;
    int d = threadIdx.x;
    float v = src[(size_t)idx[(size_t)r * istride] * DD + d];
    float ss = v * v;
#pragma unroll
    for (int o = 32; o >= 1; o >>= 1) ss += __shfl_xor(ss, o);
    out[(size_t)r * DD + d] = v * rsqrtf(ss + 1e-8f);
}

// out[64][n] = in[n][64]^T
__global__ void transpose64_kernel(float* __restrict__ out, const float* __restrict__ in,
                                   int n) {
    __shared__ float T[64][65];
    int b0 = blockIdx.x * 64;
    int t = threadIdx.x;
#pragma unroll
    for (int k = 0; k < 4; ++k) {
        int f = k * 1024 + t * 4;
        int r = f >> 6, c = f & 63;
        float4 v = *(const float4*)(in + (size_t)(b0 + r) * 64 + c);
        T[r][c] = v.x; T[r][c + 1] = v.y; T[r][c + 2] = v.z; T[r][c + 3] = v.w;
    }
    __syncthreads();
#pragma unroll
    for (int k = 0; k < 4; ++k) {
        int f = k * 1024 + t * 4;
        int d = f >> 6, c = f & 63;
        float4 v;
        v.x = T[c][d]; v.y = T[c + 1][d]; v.z = T[c + 2][d]; v.w = T[c + 3][d];
        *(float4*)(out + (size_t)d * n + b0 + c) = v;
    }
}

__global__ void batch_pred_kernel(const float* __restrict__ u1, const float* __restrict__ u2,
                                  const float* __restrict__ u3b,
                                  const float* __restrict__ b1, const float* __restrict__ b2,
                                  const float* __restrict__ b3,
                                  const int* __restrict__ uidx, const int* __restrict__ bidx,
                                  const float* __restrict__ W1, const float* __restrict__ c1,
                                  const float* __restrict__ W2, const float* __restrict__ c2,
                                  const float* __restrict__ W3, const float* __restrict__ c3,
                                  float* __restrict__ acc, int nb) {
    int b = blockIdx.x;
    if (b >= nb) return;
    int d = threadIdx.x;
    int u = uidx[b];
    float ud1 = u1[(size_t)u * DD + d];
    float ud2 = u2[(size_t)u * DD + d];
    float ud3 = u3b[(size_t)b * DD + d];
    float pred[2];
#pragma unroll
    for (int p = 0; p < 2; ++p) {
        int bi = bidx[b * 2 + p];
        float s0 = ud1 * b1[(size_t)bi * DD + d];
        float s1 = ud2 * b2[(size_t)bi * DD + d];
        float s2 = ud3 * b3[(size_t)bi * DD + d];
#pragma unroll
        for (int o = 32; o >= 1; o >>= 1) {
            s0 += __shfl_xor(s0, o);
            s1 += __shfl_xor(s1, o);
            s2 += __shfl_xor(s2, o);
        }
        float t0 = tanhf(s0 * W1[0] + s1 * W1[1] + s2 * W1[2] + c1[0]);
        float t1 = tanhf(s0 * W1[3] + s1 * W1[4] + s2 * W1[5] + c1[1]);
        float t2 = tanhf(s0 * W1[6] + s1 * W1[7] + s2 * W1[8] + c1[2]);
        float g0 = tanhf(t0 * W2[0] + t1 * W2[1] + t2 * W2[2] + c2[0]);
        float g1 = tanhf(t0 * W2[3] + t1 * W2[4] + t2 * W2[5] + c2[1]);
        float g2 = tanhf(t0 * W2[6] + t1 * W2[7] + t2 * W2[8] + c2[2]);
        pred[p] = g0 * W3[0] + g1 * W3[1] + g2 * W3[2] + c3[0];
    }
    if (d == 0) {
        float x = pred[1] - pred[0];
        float sp = (x > 20.0f) ? x : log1pf(expf(x));
        unsafeAtomicAdd(acc, sp);
    }
}

// per row i (1 wave): logsumexp_j(A_i . Bt_j / temp) - diag; Bt is d-major [64][n]
__global__ void nce_kernel(const float* __restrict__ A, const float* __restrict__ Bt,
                           float* __restrict__ acc, int n, float invtemp) {
    int wv = threadIdx.x >> 6;
    int lane = threadIdx.x & 63;
    int row = blockIdx.x * 4 + wv;
    float4 a4[16];
    const float4* Ap = (const float4*)(A + (size_t)row * DD);
#pragma unroll
    for (int q = 0; q < 16; ++q) a4[q] = Ap[q];
    float m = -1e30f, ssum = 0.0f, diag = 0.0f;
    int ntile = n >> 6;
    for (int t = 0; t < ntile; ++t) {
        int j = (t << 6) + lane;
        const float* c = Bt + j;
        float dot = 0.0f;
#pragma unroll
        for (int q = 0; q < 16; ++q) {
            float4 a = a4[q];
            dot += a.x * c[(size_t)(4 * q + 0) * n]
                 + a.y * c[(size_t)(4 * q + 1) * n]
                 + a.z * c[(size_t)(4 * q + 2) * n]
                 + a.w * c[(size_t)(4 * q + 3) * n];
        }
        float lg = dot * invtemp;
        if (j == row) diag = lg;
        float mn = fmaxf(m, lg);
        ssum = ssum * __expf(m - mn) + __expf(lg - mn);
        m = mn;
    }
#pragma unroll
    for (int o = 32; o >= 1; o >>= 1) {
        float m2 = __shfl_xor(m, o);
        float s2 = __shfl_xor(ssum, o);
        float d2 = __shfl_xor(diag, o);
        float mn = fmaxf(m, m2);
        ssum = ssum * __expf(m - mn) + s2 * __expf(m2 - mn);
        m = mn;
        diag += d2;
    }
    if (lane == 0) unsafeAtomicAdd(acc, m + logf(ssum) - diag);
}

__global__ void final_kernel(const float* __restrict__ acc, float* __restrict__ out,
                             float invn, float alpha) {
    out[0] = acc[0] * invn + alpha * invn * (acc[1] + acc[2]);
}

// ================================ driver ==================================

extern "C" void kernel_launch(void* const* d_in, const int* in_sizes, int n_in,
                              void* d_out, int out_size, void* d_ws, size_t ws_size,
                              hipStream_t stream) {
    const float* users_feat   = (const float*)d_in[0];
    const float* bundles_feat = (const float*)d_in[1];
    const float* items_feat   = (const float*)d_in[2];
    const float* W1 = (const float*)d_in[3];
    const float* c1 = (const float*)d_in[4];
    const float* W2 = (const float*)d_in[5];
    const float* c2 = (const float*)d_in[6];
    const float* W3 = (const float*)d_in[7];
    const float* c3 = (const float*)d_in[8];
    const float* ui_val = (const float*)d_in[9];
    const float* ub_val = (const float*)d_in[10];
    const float* bi_val = (const float*)d_in[11];
    const int* ui_row = (const int*)d_in[12];
    const int* ui_col = (const int*)d_in[13];
    const int* ub_row = (const int*)d_in[14];
    const int* ub_col = (const int*)d_in[15];
    const int* bi_row = (const int*)d_in[16];
    const int* bi_col = (const int*)d_in[17];
    const int* uidx = (const int*)d_in[18];
    const int* bidx = (const int*)d_in[19];

    const int U  = in_sizes[0] / DD;
    const int NB = in_sizes[1] / DD;
    const int I  = in_sizes[2] / DD;
    const int Eui = in_sizes[9];
    const int Eub = in_sizes[10];
    const int Ebi = in_sizes[11];
    const int BT = in_sizes[18];

    const size_t U64  = (size_t)U * DD;
    const size_t I64  = (size_t)I * DD;
    const size_t NB64 = (size_t)NB * DD;
    size_t R2sz = 2 * I64; if (R2sz < U64) R2sz = U64;

    // ---------------- float buffer layout (overlaid) ----------------
    float* w = (float*)d_ws;
    size_t o = 0;
    float* T_U1 = w + o; o += U64;    // x1a, then y1a
    float* R2   = w + o; o += R2sz;   // [x1b | i1] then u2
    float* T_I1 = R2;                 // x1b
    float* T_I2 = R2 + I64;           // i1
    float* u2   = R2;
    float* u1   = w + o; o += U64;
    float* b1   = w + o; o += NB64;
    float* b3   = w + o; o += NB64;
    float* y1b  = w + o; o += NB64;
    float* b2   = w + o; o += NB64;
    float* u3b  = w + o; o += (size_t)BT * DD;
    float* A1   = w + o; o += (size_t)BT * DD;
    float* A2   = w + o; o += (size_t)BT * DD;
    float* B1n  = w + o; o += (size_t)BT * DD;
    float* B2n  = w + o; o += (size_t)BT * DD;
    float* acc  = w + o; o += 16;

    // ---------------- int area: shared cnt/ptr/blocksum/perm ----------------
    int nmax = U; if (I > nmax) nmax = I; if (NB > nmax) nmax = NB;
    int emax = Eui; if (Eub > emax) emax = Eub; if (Ebi > emax) emax = Ebi;
    int* ib = (int*)(w + o);
    size_t io_ = 0;
    int* cnt  = ib + io_; io_ += (size_t)nmax + 1;   // also scatter cursor
    int* ptr_ = ib + io_; io_ += (size_t)nmax + 1;
    int* bsum = ib + io_; io_ += 1025;
    int* perm = ib + io_; io_ += (size_t)emax;
    size_t needed = o * sizeof(float) + io_ * sizeof(int);

    // transposed NCE operands overlay the (dead-by-then) int area
    float* A2t = (float*)ib;                       // [64][BT]
    float* B2t = A2t + (size_t)BT * DD;            // [64][BT]

    auto avg3 = [&](float* io2, const float* a, const float* b, long long n) {
        long long n4 = n / 4;
        long long nb_ = (n4 + 255) / 256;
        int blocks = (int)(nb_ > 4096 ? 4096 : nb_);
        avg3_kernel<<<blocks, 256, 0, stream>>>((float4*)io2, (const float4*)a,
                                                (const float4*)b, n4);
    };

    if (ws_size >= needed) {
        // ---------------- CSR gather path (no float atomics) ----------------
        auto build = [&](const int* tgt, int n, int E) {
            hipMemsetAsync(cnt, 0, ((size_t)n + 1) * sizeof(int), stream);
            int gb = (E + 255) / 256; if (gb > 8192) gb = 8192;
            hist_kernel<<<gb, 256, 0, stream>>>(cnt, tgt, E);
            int nb_ = (n + SCAN_EPB - 1) / SCAN_EPB;
            scan_pass1<<<nb_, SCAN_TPB, 0, stream>>>(bsum, cnt, n);
            scan_pass2<<<1, 1024, 0, stream>>>(bsum, nb_, ptr_ + n);
            scan_pass3<<<nb_, SCAN_TPB, 0, stream>>>(ptr_, cnt, cnt, bsum, n);  // cursor=cnt
            scatter_perm_kernel<<<gb, 256, 0, stream>>>(perm, cnt, tgt, E);
        };
        auto spmm = [&](float* out_, const float* in_, const int* srcarr,
                        const float* valarr, int nrows,
                        const float* add1, const float* add2, float scale1,
                        const float* in2, float* out2, const float* addB,
                        float f, float scale2) {
            int blocks = (nrows + 3) / 4;
            spmm_csr_kernel<<<blocks, 256, 0, stream>>>(out_, in_, perm, ptr_,
                                                        srcarr, valarr, nrows,
                                                        add1, add2, scale1,
                                                        in2, out2, addB, f, scale2);
        };
        const float k3 = 1.0f / 3.0f;

        // ---- View 1 (u-i); u3 == x1a ----
        build(ui_row, U, Eui);
        spmm(T_U1, items_feat, ui_col, ui_val, U,
             nullptr, nullptr, 1.f, nullptr, nullptr, nullptr, 0.f, 1.f);       // x1a
        gather_kernel<<<(BT * DD + 255) / 256, 256, 0, stream>>>(u3b, T_U1, uidx, BT);
        build(ui_col, I, Eui);
        spmm(T_I1, users_feat, ui_row, ui_val, I,
             nullptr, nullptr, 1.f,
             T_U1, T_I2, items_feat, 1.f, k3);                                  // x1b + i1
        build(ui_row, U, Eui);
        spmm(u1, T_I1, ui_col, ui_val, U,
             users_feat, T_U1, k3, nullptr, nullptr, nullptr, 0.f, 1.f);        // u1
        build(bi_row, NB, Ebi);
        spmm(b1, T_I2, bi_col, bi_val, NB,
             nullptr, nullptr, 1.f,
             items_feat, b3, nullptr, 0.f, 1.f);                                // b1 + b3

        // ---- View 2 (u-b) ----
        build(ub_row, U, Eub);
        spmm(T_U1, bundles_feat, ub_col, ub_val, U,
             nullptr, nullptr, 1.f, nullptr, nullptr, nullptr, 0.f, 1.f);       // y1a
        build(ub_col, NB, Eub);
        spmm(y1b, users_feat, ub_row, ub_val, NB,
             nullptr, nullptr, 1.f,
             T_U1, b2, bundles_feat, 1.f, k3);                                  // y1b + b2
        build(ub_row, U, Eub);
        spmm(u2, y1b, ub_col, ub_val, U,
             users_feat, T_U1, k3, nullptr, nullptr, nullptr, 0.f, 1.f);        // u2
    } else {
        // ---------------- atomic fallback ----------------
        auto spmm_at = [&](float* out_, const float* in_, const int* tgt, const int* src,
                           const float* val, int E, size_t outfloats) {
            hipMemsetAsync(out_, 0, outfloats * sizeof(float), stream);
            long long nwork = (long long)E * 16;
            long long nb_ = (nwork + 255) / 256;
            int blocks = (int)(nb_ > 16384 ? 16384 : nb_);
            spmm_atomic_kernel<<<blocks, 256, 0, stream>>>(out_, in_, tgt, src, val, nwork);
        };
        spmm_at(T_U1, items_feat, ui_row, ui_col, ui_val, Eui, U64);
        spmm_at(T_I1, users_feat, ui_col, ui_row, ui_val, Eui, I64);
        spmm_at(T_I2, T_U1, ui_col, ui_row, ui_val, Eui, I64);
        spmm_at(u1, T_I1, ui_row, ui_col, ui_val, Eui, U64);
        gather_kernel<<<(BT * DD + 255) / 256, 256, 0, stream>>>(u3b, T_U1, uidx, BT);
        avg3(u1, users_feat, T_U1, (long long)U64);
        avg3(T_I2, items_feat, T_I1, (long long)I64);
        spmm_at(b1, T_I2, bi_row, bi_col, bi_val, Ebi, NB64);
        spmm_at(b3, items_feat, bi_row, bi_col, bi_val, Ebi, NB64);
        spmm_at(T_U1, bundles_feat, ub_row, ub_col, ub_val, Eub, U64);
        spmm_at(y1b, users_feat, ub_col, ub_row, ub_val, Eub, NB64);
        spmm_at(b2, T_U1, ub_col, ub_row, ub_val, Eub, NB64);
        spmm_at(u2, y1b, ub_row, ub_col, ub_val, Eub, U64);
        avg3(u2, users_feat, T_U1, (long long)U64);
        avg3(b2, bundles_feat, y1b, (long long)NB64);
    }

    // ---- batch gathers + normalized views for InfoNCE ----
    gather_norm_kernel<<<BT, 64, 0, stream>>>(A1, u1, uidx, BT, 1);
    gather_norm_kernel<<<BT, 64, 0, stream>>>(A2, u2, uidx, BT, 1);
    gather_norm_kernel<<<BT, 64, 0, stream>>>(B1n, b1, bidx, BT, 2);
    gather_norm_kernel<<<BT, 64, 0, stream>>>(B2n, b2, bidx, BT, 2);
    // transpose the B-side operands (into dead CSR area)
    transpose64_kernel<<<BT / 64, 256, 0, stream>>>(A2t, A2, BT);
    transpose64_kernel<<<BT / 64, 256, 0, stream>>>(B2t, B2n, BT);

    hipMemsetAsync(acc, 0, 4 * sizeof(float), stream);

    batch_pred_kernel<<<BT, 64, 0, stream>>>(u1, u2, u3b, b1, b2, b3, uidx, bidx,
                                             W1, c1, W2, c2, W3, c3, acc, BT);

    nce_kernel<<<BT / 4, 256, 0, stream>>>(A1, A2t, acc + 1, BT, 4.0f);
    nce_kernel<<<BT / 4, 256, 0, stream>>>(B1n, B2t, acc + 2, BT, 4.0f);

    final_kernel<<<1, 1, 0, stream>>>(acc, (float*)d_out, 1.0f / (float)BT, 0.5f);
}

// Round 6
// 3097.688 us; speedup vs baseline: 2.4358x; 1.6822x over previous
//
#include <hip/hip_runtime.h>
#include <math.h>

#define DD 64
#define SCAN_TPB 256
#define SCAN_EPT 8
#define SCAN_EPB (SCAN_TPB * SCAN_EPT)  // 2048 elements per block

// ============================ CSR build kernels ============================

__global__ void hist_kernel(int* __restrict__ cnt, const int* __restrict__ tgt, int E) {
    int g = blockIdx.x * blockDim.x + threadIdx.x;
    int stride = gridDim.x * blockDim.x;
    for (int e = g; e < E; e += stride) atomicAdd(&cnt[tgt[e]], 1);
}

__global__ void scan_pass1(int* __restrict__ blocksum, const int* __restrict__ cnt, int n) {
    int base = blockIdx.x * SCAN_EPB + threadIdx.x * SCAN_EPT;
    int s = 0;
#pragma unroll
    for (int k = 0; k < SCAN_EPT; ++k) {
        int i = base + k;
        if (i < n) s += cnt[i];
    }
#pragma unroll
    for (int o = 32; o >= 1; o >>= 1) s += __shfl_xor(s, o);
    __shared__ int ws_[4];
    if ((threadIdx.x & 63) == 0) ws_[threadIdx.x >> 6] = s;
    __syncthreads();
    if (threadIdx.x == 0) blocksum[blockIdx.x] = ws_[0] + ws_[1] + ws_[2] + ws_[3];
}

__global__ void scan_pass2(int* __restrict__ blocksum, int nb, int* __restrict__ ptr_n) {
    __shared__ int sh[1024];
    int t = threadIdx.x;
    int v = (t < nb) ? blocksum[t] : 0;
    sh[t] = v;
    __syncthreads();
    for (int o = 1; o < 1024; o <<= 1) {
        int x = (t >= o) ? sh[t - o] : 0;
        __syncthreads();
        sh[t] += x;
        __syncthreads();
    }
    if (t < nb) blocksum[t] = sh[t] - v;  // exclusive
    if (t == nb - 1) ptr_n[0] = sh[t];
}

// ptr[i] = cursor[i] = blockoff + intra-block exclusive scan (cursor may alias cnt)
__global__ void scan_pass3(int* __restrict__ ptr, int* __restrict__ cursor,
                           const int* __restrict__ cnt, const int* __restrict__ blockoff,
                           int n) {
    int base = blockIdx.x * SCAN_EPB + threadIdx.x * SCAN_EPT;
    int vals[SCAN_EPT];
    int s = 0;
#pragma unroll
    for (int k = 0; k < SCAN_EPT; ++k) {
        int i = base + k;
        int c = (i < n) ? cnt[i] : 0;
        vals[k] = s;
        s += c;
    }
    int incl = s;
#pragma unroll
    for (int o = 1; o < 64; o <<= 1) {
        int x = __shfl_up(incl, o);
        if ((threadIdx.x & 63) >= o) incl += x;
    }
    __shared__ int wtot[4];
    if ((threadIdx.x & 63) == 63) wtot[threadIdx.x >> 6] = incl;
    __syncthreads();
    int woff = 0;
    int wv = threadIdx.x >> 6;
    for (int k = 0; k < 4; ++k)
        if (k < wv) woff += wtot[k];
    int texcl = incl - s + woff + blockoff[blockIdx.x];
#pragma unroll
    for (int k = 0; k < SCAN_EPT; ++k) {
        int i = base + k;
        if (i < n) {
            int p = texcl + vals[k];
            ptr[i] = p;
            cursor[i] = p;
        }
    }
}

// pairs[pos] = {src[e], val[e]} grouped by tgt[e]; cursor pre-loaded with ptr
__global__ void scatter_pairs_kernel(int2* __restrict__ pairs, int* __restrict__ cursor,
                                     const int* __restrict__ tgt, const int* __restrict__ src,
                                     const float* __restrict__ val, int E) {
    int g = blockIdx.x * blockDim.x + threadIdx.x;
    int stride = gridDim.x * blockDim.x;
    for (int e = g; e < E; e += stride) {
        int2 pr;
        pr.x = src[e];
        pr.y = __float_as_int(val[e]);
        int p = atomicAdd(&cursor[tgt[e]], 1);
        pairs[p] = pr;
    }
}

// ======================= gather-based segmented SpMM =======================
// one wave per output row; lane = dim.
//   acc  = sum_e val_e * in [src_e];   acc2 = sum_e val_e * in2[src_e]
//   out [r] = (acc  + add1[r] + add2[r]) * scale1        (add2 may alias out)
//   out2[r] = (acc2 + f*acc  + addB[r]) * scale2         (dual only)
__global__ void spmm_csr_kernel(float* __restrict__ out, const float* __restrict__ in,
                                const int2* __restrict__ pairs, const int* __restrict__ ptr,
                                int nrows,
                                const float* __restrict__ add1, const float* __restrict__ add2,
                                float scale1,
                                const float* __restrict__ in2, float* __restrict__ out2,
                                const float* __restrict__ addB, float f, float scale2) {
    int w = (int)(((unsigned)blockIdx.x * blockDim.x + threadIdx.x) >> 6);
    int lane = threadIdx.x & 63;
    if (w >= nrows) return;
    int p = ptr[w];
    int end = ptr[w + 1];
    size_t rowoff = (size_t)w * DD + lane;
    float acc = 0.f, acc2 = 0.f;
    const bool dual = (in2 != nullptr);
    for (; p + 8 <= end; p += 8) {
        int ss[8];
        float vv[8];
#pragma unroll
        for (int k = 0; k < 8; ++k) {
            int2 pr = pairs[p + k];
            ss[k] = __builtin_amdgcn_readfirstlane(pr.x);
            vv[k] = __int_as_float(__builtin_amdgcn_readfirstlane(pr.y));
        }
#pragma unroll
        for (int k = 0; k < 8; ++k) acc += vv[k] * in[(size_t)ss[k] * DD + lane];
        if (dual) {
#pragma unroll
            for (int k = 0; k < 8; ++k) acc2 += vv[k] * in2[(size_t)ss[k] * DD + lane];
        }
    }
    for (; p < end; ++p) {
        int2 pr = pairs[p];
        int s = __builtin_amdgcn_readfirstlane(pr.x);
        float v = __int_as_float(__builtin_amdgcn_readfirstlane(pr.y));
        acc += v * in[(size_t)s * DD + lane];
        if (dual) acc2 += v * in2[(size_t)s * DD + lane];
    }
    float r = acc;
    if (add1) r += add1[rowoff];
    if (add2) r += add2[rowoff];
    out[rowoff] = r * scale1;
    if (dual) {
        float r2 = acc2 + f * acc;
        if (addB) r2 += addB[rowoff];
        out2[rowoff] = r2 * scale2;
    }
}

// ============================= dense helpers ==============================

// raw[r] = src[idx[r*istride]]  (one 64-thread block row-chunk)
__global__ void gather_rows_kernel(float* __restrict__ raw, const float* __restrict__ src,
                                   const int* __restrict__ idx, int nrows, int istride) {
    int g = blockIdx.x * blockDim.x + threadIdx.x;
    if (g >= nrows * DD) return;
    int r = g >> 6;
    raw[g] = src[(size_t)idx[(size_t)r * istride] * DD + (g & 63)];
}

// raw[r] = src[idx[r*istride]], nrm[r] = normalize(raw[r])  (1 wave per row)
__global__ void gather_rows_norm_kernel(float* __restrict__ raw, float* __restrict__ nrm,
                                        const float* __restrict__ src,
                                        const int* __restrict__ idx, int nrows, int istride) {
    int r = blockIdx.x;
    if (r >= nrows) return;
    int d = threadIdx.x;
    float v = src[(size_t)idx[(size_t)r * istride] * DD + d];
    if (raw) raw[(size_t)r * DD + d] = v;
    float ss = v * v;
#pragma unroll
    for (int o = 32; o >= 1; o >>= 1) ss += __shfl_xor(ss, o);
    nrm[(size_t)r * DD + d] = v * rsqrtf(ss + 1e-8f);
}

// out[64][n] = in[n][64]^T
__global__ void transpose64_kernel(float* __restrict__ out, const float* __restrict__ in,
                                   int n) {
    __shared__ float T[64][65];
    int b0 = blockIdx.x * 64;
    int t = threadIdx.x;
#pragma unroll
    for (int k = 0; k < 4; ++k) {
        int f = k * 1024 + t * 4;
        int r = f >> 6, c = f & 63;
        float4 v = *(const float4*)(in + (size_t)(b0 + r) * 64 + c);
        T[r][c] = v.x; T[r][c + 1] = v.y; T[r][c + 2] = v.z; T[r][c + 3] = v.w;
    }
    __syncthreads();
#pragma unroll
    for (int k = 0; k < 4; ++k) {
        int f = k * 1024 + t * 4;
        int d = f >> 6, c = f & 63;
        float4 v;
        v.x = T[c][d]; v.y = T[c + 1][d]; v.z = T[c + 2][d]; v.w = T[c + 3][d];
        *(float4*)(out + (size_t)d * n + b0 + c) = v;
    }
}

// all operands pre-gathered to batch order
__global__ void batch_pred_kernel(const float* __restrict__ u1b, const float* __restrict__ u2b,
                                  const float* __restrict__ u3b,
                                  const float* __restrict__ b1b, const float* __restrict__ b2b,
                                  const float* __restrict__ b3b,
                                  const float* __restrict__ W1, const float* __restrict__ c1,
                                  const float* __restrict__ W2, const float* __restrict__ c2,
                                  const float* __restrict__ W3, const float* __restrict__ c3,
                                  float* __restrict__ acc, int nb) {
    int b = blockIdx.x;
    if (b >= nb) return;
    int d = threadIdx.x;
    float ud1 = u1b[(size_t)b * DD + d];
    float ud2 = u2b[(size_t)b * DD + d];
    float ud3 = u3b[(size_t)b * DD + d];
    float pred[2];
#pragma unroll
    for (int p = 0; p < 2; ++p) {
        size_t r = (size_t)(b * 2 + p) * DD + d;
        float s0 = ud1 * b1b[r];
        float s1 = ud2 * b2b[r];
        float s2 = ud3 * b3b[r];
#pragma unroll
        for (int o = 32; o >= 1; o >>= 1) {
            s0 += __shfl_xor(s0, o);
            s1 += __shfl_xor(s1, o);
            s2 += __shfl_xor(s2, o);
        }
        float t0 = tanhf(s0 * W1[0] + s1 * W1[1] + s2 * W1[2] + c1[0]);
        float t1 = tanhf(s0 * W1[3] + s1 * W1[4] + s2 * W1[5] + c1[1]);
        float t2 = tanhf(s0 * W1[6] + s1 * W1[7] + s2 * W1[8] + c1[2]);
        float g0 = tanhf(t0 * W2[0] + t1 * W2[1] + t2 * W2[2] + c2[0]);
        float g1 = tanhf(t0 * W2[3] + t1 * W2[4] + t2 * W2[5] + c2[1]);
        float g2 = tanhf(t0 * W2[6] + t1 * W2[7] + t2 * W2[8] + c2[2]);
        pred[p] = g0 * W3[0] + g1 * W3[1] + g2 * W3[2] + c3[0];
    }
    if (d == 0) {
        float x = pred[1] - pred[0];
        float sp = (x > 20.0f) ? x : log1pf(expf(x));
        unsafeAtomicAdd(acc, sp);
    }
}

// per row (1 wave): logsumexp_j(A_i . Bt_j / temp) - diag; Bt d-major [64][n].
// lane covers 4 consecutive columns -> float4 (1KB/wave) coalesced loads.
__global__ void nce_kernel(const float* __restrict__ A, const float* __restrict__ Bt,
                           float* __restrict__ acc, int n, float invtemp) {
    int wv = threadIdx.x >> 6;
    int lane = threadIdx.x & 63;
    int row = blockIdx.x * 4 + wv;
    float4 a4[16];
    const float4* Ap = (const float4*)(A + (size_t)row * DD);
#pragma unroll
    for (int q = 0; q < 16; ++q) a4[q] = Ap[q];
    float m = -1e30f, ssum = 0.0f, diag = 0.0f;
    int ntile = n >> 8;  // 256 columns per tile
    for (int t = 0; t < ntile; ++t) {
        int j0 = (t << 8) + (lane << 2);
        float dx = 0.f, dy = 0.f, dz = 0.f, dw = 0.f;
#pragma unroll
        for (int q = 0; q < 16; ++q) {
            float4 a = a4[q];
            float4 r0 = *(const float4*)(Bt + (size_t)(4 * q + 0) * n + j0);
            float4 r1 = *(const float4*)(Bt + (size_t)(4 * q + 1) * n + j0);
            float4 r2 = *(const float4*)(Bt + (size_t)(4 * q + 2) * n + j0);
            float4 r3 = *(const float4*)(Bt + (size_t)(4 * q + 3) * n + j0);
            dx += a.x * r0.x + a.y * r1.x + a.z * r2.x + a.w * r3.x;
            dy += a.x * r0.y + a.y * r1.y + a.z * r2.y + a.w * r3.y;
            dz += a.x * r0.z + a.y * r1.z + a.z * r2.z + a.w * r3.z;
            dw += a.x * r0.w + a.y * r1.w + a.z * r2.w + a.w * r3.w;
        }
        float lg[4] = {dx * invtemp, dy * invtemp, dz * invtemp, dw * invtemp};
#pragma unroll
        for (int k = 0; k < 4; ++k) {
            if (j0 + k == row) diag = lg[k];
            float mn = fmaxf(m, lg[k]);
            ssum = ssum * __expf(m - mn) + __expf(lg[k] - mn);
            m = mn;
        }
    }
#pragma unroll
    for (int o = 32; o >= 1; o >>= 1) {
        float m2 = __shfl_xor(m, o);
        float s2 = __shfl_xor(ssum, o);
        float d2 = __shfl_xor(diag, o);
        float mn = fmaxf(m, m2);
        ssum = ssum * __expf(m - mn) + s2 * __expf(m2 - mn);
        m = mn;
        diag += d2;
    }
    if (lane == 0) unsafeAtomicAdd(acc, m + logf(ssum) - diag);
}

__global__ void final_kernel(const float* __restrict__ acc, float* __restrict__ out,
                             float invn, float alpha) {
    out[0] = acc[0] * invn + alpha * invn * (acc[1] + acc[2]);
}

// ================================ driver ==================================
// ws proven >= 236 MB (R1 atomic layout ran validated). This layout needs ~185 MB.

extern "C" void kernel_launch(void* const* d_in, const int* in_sizes, int n_in,
                              void* d_out, int out_size, void* d_ws, size_t ws_size,
                              hipStream_t stream) {
    const float* users_feat   = (const float*)d_in[0];
    const float* bundles_feat = (const float*)d_in[1];
    const float* items_feat   = (const float*)d_in[2];
    const float* W1 = (const float*)d_in[3];
    const float* c1 = (const float*)d_in[4];
    const float* W2 = (const float*)d_in[5];
    const float* c2 = (const float*)d_in[6];
    const float* W3 = (const float*)d_in[7];
    const float* c3 = (const float*)d_in[8];
    const float* ui_val = (const float*)d_in[9];
    const float* ub_val = (const float*)d_in[10];
    const float* bi_val = (const float*)d_in[11];
    const int* ui_row = (const int*)d_in[12];
    const int* ui_col = (const int*)d_in[13];
    const int* ub_row = (const int*)d_in[14];
    const int* ub_col = (const int*)d_in[15];
    const int* bi_row = (const int*)d_in[16];
    const int* bi_col = (const int*)d_in[17];
    const int* uidx = (const int*)d_in[18];
    const int* bidx = (const int*)d_in[19];

    const int U  = in_sizes[0] / DD;
    const int NB = in_sizes[1] / DD;
    const int I  = in_sizes[2] / DD;
    const int Eui = in_sizes[9];
    const int Eub = in_sizes[10];
    const int Ebi = in_sizes[11];
    const int BT = in_sizes[18];

    const size_t U64  = (size_t)U * DD;
    const size_t I64  = (size_t)I * DD;
    const size_t NB64 = (size_t)NB * DD;
    const size_t BT64 = (size_t)BT * DD;
    size_t R2sz = 2 * I64; if (R2sz < U64) R2sz = U64;
    if (R2sz < 2 * NB64) R2sz = 2 * NB64;

    // ---------------- float buffers ----------------
    float* w = (float*)d_ws;
    size_t o = 0;
    float* BUF_U = w + o; o += U64;          // x1a -> u1(in-place) -> y1a -> u2(in-place)
    float* R2    = w + o; o += R2sz;         // [x1b | i1] -> [b1 | b3] -> [y1b | b2]
    float* RA    = R2;                       // x1b / b1 / y1b
    float* RB    = R2 + (R2sz / 2);          // i1 / b3 / b2
    float* u3b = w + o; o += BT64;
    float* u1b = w + o; o += BT64;
    float* u2b = w + o; o += BT64;
    float* b1b = w + o; o += 2 * BT64;
    float* b2b = w + o; o += 2 * BT64;
    float* b3b = w + o; o += 2 * BT64;
    float* A1  = w + o; o += BT64;
    float* A2  = w + o; o += BT64;
    float* B1n = w + o; o += BT64;
    float* B2n = w + o; o += BT64;
    float* acc = w + o; o += 16;

    // ---------------- int area ----------------
    int nmax = U; if (I > nmax) nmax = I; if (NB > nmax) nmax = NB;
    int emax = Eui; if (Eub > emax) emax = Eub; if (Ebi > emax) emax = Ebi;
    int* ib = (int*)(w + o);
    size_t io_ = 0;
    int* cnt  = ib + io_; io_ += (size_t)nmax + 1;   // also scatter cursor
    int* bsum = ib + io_; io_ += 1025;
    int* ptrA = ib + io_; io_ += (size_t)nmax + 1;
    int* ptrB = ib + io_; io_ += (size_t)nmax + 1;
    io_ = (io_ + 3) & ~(size_t)3;                    // 16B align for pairs/overlay
    int2* pairsA = (int2*)(ib + io_); io_ += (size_t)emax * 2;
    int2* pairsB = (int2*)(ib + io_); io_ += (size_t)emax * 2;

    // NCE transposed operands overlay pairsA (dead after last spmm)
    float* A2t = (float*)pairsA;           // [64][BT]
    float* B2t = A2t + BT64;               // [64][BT]

    auto build = [&](int2* pairs, int* ptr_, const int* tgt, const int* src,
                     const float* val, int n, int E) {
        hipMemsetAsync(cnt, 0, ((size_t)n + 1) * sizeof(int), stream);
        int gb = (E + 255) / 256; if (gb > 8192) gb = 8192;
        hist_kernel<<<gb, 256, 0, stream>>>(cnt, tgt, E);
        int nb_ = (n + SCAN_EPB - 1) / SCAN_EPB;
        scan_pass1<<<nb_, SCAN_TPB, 0, stream>>>(bsum, cnt, n);
        scan_pass2<<<1, 1024, 0, stream>>>(bsum, nb_, ptr_ + n);
        scan_pass3<<<nb_, SCAN_TPB, 0, stream>>>(ptr_, cnt, cnt, bsum, n);  // cursor=cnt
        scatter_pairs_kernel<<<gb, 256, 0, stream>>>(pairs, cnt, tgt, src, val, E);
    };
    auto spmm = [&](float* out_, const float* in_, const int2* pairs, const int* ptr_,
                    int nrows, const float* add1, const float* add2, float scale1,
                    const float* in2, float* out2, const float* addB, float f,
                    float scale2) {
        int blocks = (nrows + 3) / 4;
        spmm_csr_kernel<<<blocks, 256, 0, stream>>>(out_, in_, pairs, ptr_, nrows,
                                                    add1, add2, scale1,
                                                    in2, out2, addB, f, scale2);
    };
    const float k3 = 1.0f / 3.0f;
    const float* NUL = nullptr;

    // ---- View 1 (u-i); u3 == x1a ----
    build(pairsA, ptrA, ui_row, ui_col, ui_val, U, Eui);
    spmm(BUF_U, items_feat, pairsA, ptrA, U, NUL, NUL, 1.f, NUL, nullptr, NUL, 0.f, 1.f); // x1a
    gather_rows_kernel<<<(BT * DD + 255) / 256, 256, 0, stream>>>(u3b, BUF_U, uidx, BT, 1);
    build(pairsB, ptrB, ui_col, ui_row, ui_val, I, Eui);
    spmm(RA, users_feat, pairsB, ptrB, I, NUL, NUL, 1.f,
         BUF_U, RB, items_feat, 1.f, k3);                                  // x1b + i1
    spmm(BUF_U, RA, pairsA, ptrA, U, users_feat, BUF_U, k3,
         NUL, nullptr, NUL, 0.f, 1.f);                                     // u1 (in-place)
    gather_rows_norm_kernel<<<BT, 64, 0, stream>>>(u1b, A1, BUF_U, uidx, BT, 1);

    // ---- b1 + b3 (bi graph) ----
    build(pairsA, ptrA, bi_row, bi_col, bi_val, NB, Ebi);   // pairsA reused (ui_row done)
    // b1/b3 write over RA region (x1b dead); i1 stays in RB until read here... careful:
    // in = RB (i1); outputs must not alias RB. Place b1 at RA, b3 at RA+NB64 (RA half is I64 >= 2*NB64? I=100k,NB=50k -> I64=6.4M = 2*NB64 exactly)
    spmm(RA, RB, pairsA, ptrA, NB, NUL, NUL, 1.f,
         items_feat, RA + NB64, NUL, 0.f, 1.f);                            // b1 + b3
    gather_rows_kernel<<<(2 * BT * DD + 255) / 256, 256, 0, stream>>>(b1b, RA, bidx, 2 * BT, 1);
    gather_rows_kernel<<<(2 * BT * DD + 255) / 256, 256, 0, stream>>>(b3b, RA + NB64, bidx, 2 * BT, 1);
    gather_rows_norm_kernel<<<BT, 64, 0, stream>>>(nullptr, B1n, RA, bidx, BT, 2);

    // ---- View 2 (u-b) ----
    build(pairsA, ptrA, ub_row, ub_col, ub_val, U, Eub);
    spmm(BUF_U, bundles_feat, pairsA, ptrA, U, NUL, NUL, 1.f,
         NUL, nullptr, NUL, 0.f, 1.f);                                     // y1a
    build(pairsB, ptrB, ub_col, ub_row, ub_val, NB, Eub);
    spmm(RA, users_feat, pairsB, ptrB, NB, NUL, NUL, 1.f,
         BUF_U, RB, bundles_feat, 1.f, k3);                                // y1b + b2
    spmm(BUF_U, RA, pairsA, ptrA, U, users_feat, BUF_U, k3,
         NUL, nullptr, NUL, 0.f, 1.f);                                     // u2 (in-place)
    gather_rows_norm_kernel<<<BT, 64, 0, stream>>>(u2b, A2, BUF_U, uidx, BT, 1);
    gather_rows_kernel<<<(2 * BT * DD + 255) / 256, 256, 0, stream>>>(b2b, RB, bidx, 2 * BT, 1);
    gather_rows_norm_kernel<<<BT, 64, 0, stream>>>(nullptr, B2n, RB, bidx, BT, 2);

    // ---- transposes (into dead pairs area) ----
    transpose64_kernel<<<BT / 64, 256, 0, stream>>>(A2t, A2, BT);
    transpose64_kernel<<<BT / 64, 256, 0, stream>>>(B2t, B2n, BT);

    hipMemsetAsync(acc, 0, 4 * sizeof(float), stream);

    batch_pred_kernel<<<BT, 64, 0, stream>>>(u1b, u2b, u3b, b1b, b2b, b3b,
                                             W1, c1, W2, c2, W3, c3, acc, BT);

    nce_kernel<<<BT / 4, 256, 0, stream>>>(A1, A2t, acc + 1, BT, 4.0f);
    nce_kernel<<<BT / 4, 256, 0, stream>>>(B1n, B2t, acc + 2, BT, 4.0f);

    final_kernel<<<1, 1, 0, stream>>>(acc, (float*)d_out, 1.0f / (float)BT, 0.5f);
}